// Round 6
// baseline (1320.386 us; speedup 1.0000x reference)
//
#include <hip/hip_runtime.h>
#include <math.h>

// ---------------- constants ----------------
#define NTOK   1568
#define BATCH  2
#define HID    1024
#define MLPD   4096
#define NLAYER 4
#define ROWS   (BATCH*NTOK)   // 3136
#define CONVK  1536

typedef __bf16 bf16x8 __attribute__((ext_vector_type(8)));
typedef __bf16 bf16x2 __attribute__((ext_vector_type(2)));
typedef float  f32x4  __attribute__((ext_vector_type(4)));

__device__ __forceinline__ unsigned short f2b(float f) {
  unsigned int u = __float_as_uint(f);
  unsigned int r = u + 0x7FFFu + ((u >> 16) & 1u);   // RNE
  return (unsigned short)(r >> 16);
}
__device__ __forceinline__ float b2f(unsigned short s) {
  return __uint_as_float((unsigned int)s << 16);
}
// packed f32->bf16 pair via native casts (gfx950: v_cvt_pk_bf16_f32)
__device__ __forceinline__ unsigned cvt2(float a, float b) {
  bf16x2 t;
  t[0] = (__bf16)a;
  t[1] = (__bf16)b;
  return __builtin_bit_cast(unsigned, t);
}
__device__ __forceinline__ float e2(float x) { return __builtin_amdgcn_exp2f(x); }

// async global->LDS 16B; lds ptr must be wave-uniform base (HW adds lane*16)
__device__ __forceinline__ void async16(const unsigned short* g, unsigned short* l) {
  __builtin_amdgcn_global_load_lds(
      (__attribute__((address_space(1))) void*)(void*)g,
      (__attribute__((address_space(3))) void*)(void*)l, 16, 0, 0);
}

// ---------------- fp32 -> bf16 cast (x4 vectorized, grid-stride) ----------------
__global__ __launch_bounds__(256) void cast4_k(const float* __restrict__ s,
                                               unsigned short* __restrict__ d,
                                               long long n4) {
  long long i = (long long)blockIdx.x * 256 + threadIdx.x;
  long long stride = (long long)gridDim.x * 256;
  for (; i < n4; i += stride) {
    float4 v = ((const float4*)s)[i];
    *(ushort4*)(d + i * 4) = make_ushort4(f2b(v.x), f2b(v.y), f2b(v.z), f2b(v.w));
  }
}

// cast q/k/v weights into one concatenated per-layer buffer wQKV[L][3072][1024]
__global__ __launch_bounds__(256) void castqkv_k(const float* __restrict__ q,
                                                 const float* __restrict__ k,
                                                 const float* __restrict__ v,
                                                 unsigned short* __restrict__ dst) {
  const float* src = blockIdx.y == 0 ? q : (blockIdx.y == 1 ? k : v);
  long long i4 = (long long)blockIdx.x * 256 + threadIdx.x;   // exactly L*HH/4
  long long e = i4 * 4;
  int layer = (int)(e >> 20);                                  // HH = 1<<20
  long long de = e + ((long long)(2 * layer + blockIdx.y) << 20);
  float4 val = ((const float4*)src)[i4];
  *(ushort4*)(dst + de) = make_ushort4(f2b(val.x), f2b(val.y), f2b(val.z), f2b(val.w));
}

__global__ __launch_bounds__(256) void biascat_k(const float* __restrict__ qb,
                                                 const float* __restrict__ kb,
                                                 const float* __restrict__ vb,
                                                 float* __restrict__ dst) {
  int idx = blockIdx.x * 256 + threadIdx.x;   // L*3072
  int layer = idx / 3072, c = idx % 3072;
  float v = c < 1024 ? qb[layer * 1024 + c]
            : (c < 2048 ? kb[layer * 1024 + c - 1024] : vb[layer * 1024 + c - 2048]);
  dst[idx] = v;
}

// ---------------- im2col for the tubelet conv ----------------
__global__ __launch_bounds__(256) void im2col_k(const float* __restrict__ pv,
                                                unsigned short* __restrict__ A) {
  int idx = blockIdx.x * 256 + threadIdx.x;       // exactly ROWS*CONVK threads
  int row = idx / CONVK, col = idx % CONVK;
  int b = row / NTOK, t = row % NTOK;
  int d = t / 196, r = t % 196, hh = r / 14, ww = r % 14;
  int c = col >> 9, r2 = col & 511, td = r2 >> 8, ph = (r2 >> 4) & 15, pw = r2 & 15;
  int frame = 2 * d + td;
  const float* src = pv + ((((long long)b * 16 + frame) * 3 + c) * 224 + (hh * 16 + ph)) * 224
                        + (ww * 16 + pw);
  A[idx] = f2b(*src);
}

// ---------------- GEMM v5: 256x256 tile, 8 waves, BK=32, QUAD-buffered --------------
// out[z][M,N] = A[M,K_z](bf16) * B[N,K_z]^T(bf16). EPI: 0 raw partial, 1 +bias,
// 2 +bias+gelu (single-z gemms write final output, no reduce pass).
// Pipeline (provable ledger):
//  - 4 LDS buffers (128 KB); during step kt stage tile kt+3 -> buf (kt+3)&3.
//    Buffer free proof: buf[(kt+3)&3] = buf[(kt-1)&3], last read at step kt-1; all
//    waves passed step kt's barrier before the stage issues.
//  - gate at step top: outstanding = tiles kt+1,kt+2 (8 loads) -> vmcnt(8) retires
//    exactly tile kt; barrier makes it chip-wide. Peeled epilogue: vmcnt(4)/vmcnt(0).
//    3-step prefetch distance (~2-3k cy) >> L2/L3/HBM latency.
//  - ONLY fence: sched_barrier(0) after s_barrier (stops ds_read hoist above the
//    barrier = buffer race). No other fences: let the compiler software-pipeline
//    phase0/phase1 reads under MFMAs (m141: over-pinning defeats its scheduler).
//  - XOR involution swizzle on stage-source + ds_read (bank-conflict-free, verified
//    round 3: SQ_LDS_BANK_CONFLICT = 0); m204 bijective XCD swizzle.
template <int EPI>
__global__ __launch_bounds__(512, 2) void gemm256(const unsigned short* __restrict__ A,
                                                  const unsigned short* __restrict__ B,
                                                  unsigned short* outP,
                                                  int M, int N, int K, int kChunk,
                                                  size_t zStride,
                                                  const float* __restrict__ bias) {
  __shared__ unsigned short As[4][256 * 32];
  __shared__ unsigned short Bs[4][256 * 32];
  const int tid = threadIdx.x;
  const int lane = tid & 63;
  const int w = tid >> 6;              // 0..7
  const int wr = w >> 2, wc = w & 3;   // wave -> (2 x 4) C sub-tiles of 128x64
  const int l15 = lane & 15, l4 = lane >> 4;
  const int wbase = tid & ~63;         // wave-uniform

  // XCD-aware bijective remap of the flat workgroup id (T1, m204 formula)
  const int gx = gridDim.x, gy = gridDim.y;
  const int nwg = gx * gy * (int)gridDim.z;
  int orig = blockIdx.x + gx * (blockIdx.y + gy * blockIdx.z);
  int q = nwg >> 3, r = nwg & 7, xcd = orig & 7, idx = orig >> 3;
  int swz = (xcd < r ? xcd * (q + 1) : r * (q + 1) + (xcd - r) * q) + idx;
  const int bn = swz % gx;
  int tmp = swz / gx;
  const int bm = tmp % gy;
  const int bz = tmp / gy;
  const int kbeg = bz * kChunk;

  // staging: deposit i (16B) lands at LDS slot i (linear); source col chunk is the
  // inverse swizzle gc = (i&3) ^ ((i>>3)&3)  [row = i>>2 -> (row>>1)&3 = (i>>3)&3]
  const int r0 = tid >> 2;
  const int g0 = (tid & 3) ^ ((tid >> 3) & 3);
  const int i1 = 512 + tid;
  const int r1 = i1 >> 2;
  const int g1 = (tid & 3) ^ ((i1 >> 3) & 3);
  int ra0 = bm * 256 + r0; if (ra0 >= M) ra0 = M - 1;
  int ra1 = bm * 256 + r1; if (ra1 >= M) ra1 = M - 1;
  const int rb0 = bn * 256 + r0;       // N is always a multiple of 256
  const int rb1 = bn * 256 + r1;
  const size_t Ao0 = (size_t)ra0 * K + g0 * 8;
  const size_t Ao1 = (size_t)ra1 * K + g1 * 8;
  const size_t Bo0 = (size_t)rb0 * K + g0 * 8;
  const size_t Bo1 = (size_t)rb1 * K + g1 * 8;

  auto stA = [&](int buf, int k0) {
    async16(A + Ao0 + k0, &As[buf][wbase * 8]);
    async16(A + Ao1 + k0, &As[buf][4096 + wbase * 8]);
  };
  auto stB = [&](int buf, int k0) {
    async16(B + Bo0 + k0, &Bs[buf][wbase * 8]);
    async16(B + Bo1 + k0, &Bs[buf][4096 + wbase * 8]);
  };

  f32x4 acc[8][4] = {};
  const int nk = kChunk >> 5;          // >= 8 for all our shapes

  stA(0, kbeg); stB(0, kbeg);
  stA(1, kbeg + 32); stB(1, kbeg + 32);
  stA(2, kbeg + 64); stB(2, kbeg + 64);

  // swizzled read chunk: row = base16 + l15 with base16 % 16 == 0 -> (row>>1)&3 ==
  // (l15>>1)&3 for both A and B fragment rows
  const int pchunk = (l4 ^ ((l15 >> 1) & 3)) * 8;
  const int abase = (wr * 128 + l15) * 32 + pchunk;   // + m*512
  const int bbase = (wc * 64 + l15) * 32 + pchunk;    // + n*512

  for (int kt = 0; kt < nk; ++kt) {
    // counted gate: retire exactly tile kt (tiles kt+1, kt+2 stay in flight)
    if (kt < nk - 2) {
      asm volatile("s_waitcnt vmcnt(8)" ::: "memory");
    } else if (kt == nk - 2) {
      asm volatile("s_waitcnt vmcnt(4)" ::: "memory");
    } else {
      asm volatile("s_waitcnt vmcnt(0)" ::: "memory");
    }
    __builtin_amdgcn_s_barrier();
    __builtin_amdgcn_sched_barrier(0);   // ds_reads must not hoist above barrier
    const int cur = kt & 3;
    const int pre = (kt + 3) & 3;
    const bool doPre = (kt + 3 < nk);
    const int kpre = kbeg + (kt + 3) * 32;

    // ---- phase 0: stage A(kt+3) | read B[n0..3] + A[m0..3] | 16 MFMA
    if (doPre) stA(pre, kpre);
    bf16x8 bfr[4], af[4];
#pragma unroll
    for (int n = 0; n < 4; ++n)
      bfr[n] = *(const bf16x8*)&Bs[cur][bbase + n * 512];
#pragma unroll
    for (int m = 0; m < 4; ++m)
      af[m] = *(const bf16x8*)&As[cur][abase + m * 512];
    __builtin_amdgcn_s_setprio(1);
#pragma unroll
    for (int m = 0; m < 4; ++m)
#pragma unroll
      for (int n = 0; n < 4; ++n)
        acc[m][n] = __builtin_amdgcn_mfma_f32_16x16x32_bf16(af[m], bfr[n], acc[m][n], 0, 0, 0);
    __builtin_amdgcn_s_setprio(0);

    // ---- phase 1: stage B(kt+3) | read A[m4..7] | 16 MFMA  (no fence: compiler
    //      may overlap these reads under phase-0 MFMAs)
    if (doPre) stB(pre, kpre);
#pragma unroll
    for (int m = 0; m < 4; ++m)
      af[m] = *(const bf16x8*)&As[cur][abase + (m + 4) * 512];
    __builtin_amdgcn_s_setprio(1);
#pragma unroll
    for (int m = 0; m < 4; ++m)
#pragma unroll
      for (int n = 0; n < 4; ++n)
        acc[m + 4][n] = __builtin_amdgcn_mfma_f32_16x16x32_bf16(af[m], bfr[n], acc[m + 4][n], 0, 0, 0);
    __builtin_amdgcn_s_setprio(0);
  }

  float bsv[4] = {0, 0, 0, 0};
  if (EPI >= 1) {
#pragma unroll
    for (int n = 0; n < 4; ++n)
      bsv[n] = bias[bn * 256 + wc * 64 + n * 16 + l15];
  }
  unsigned short* pout = outP + (size_t)bz * zStride;
#pragma unroll
  for (int m = 0; m < 8; ++m) {
    int rowb = bm * 256 + wr * 128 + m * 16 + l4 * 4;
#pragma unroll
    for (int rr2 = 0; rr2 < 4; ++rr2) {
      int rr = rowb + rr2;
      if (rr >= M) continue;
#pragma unroll
      for (int n = 0; n < 4; ++n) {
        int col = bn * 256 + wc * 64 + n * 16 + l15;
        float v = acc[m][n][rr2];
        if (EPI >= 1) v += bsv[n];
        if (EPI == 2) v = 0.5f * v * (1.0f + erff(v * 0.70710678118654752f));
        pout[(size_t)rr * N + col] = f2b(v);
      }
    }
  }
}

// ---------------- fused split-K reduce + residual + LayerNorm ------------------------
template <int NP, int RESID, int FINAL>
__global__ __launch_bounds__(256) void redln_k(const unsigned short* __restrict__ p,
                                               const float* __restrict__ bias,
                                               const float* resid,
                                               const float* __restrict__ g,
                                               const float* __restrict__ b,
                                               float* hOut,
                                               unsigned short* __restrict__ xnOut,
                                               float* __restrict__ fOut,
                                               size_t pStride) {
  __shared__ float red[8];
  const int row = blockIdx.x, tid = threadIdx.x;
  const int col = tid * 4;
  const size_t off = (size_t)row * HID + col;
  float v0 = 0, v1 = 0, v2 = 0, v3 = 0;
#pragma unroll
  for (int pp = 0; pp < NP; ++pp) {
    ushort4 a = *(const ushort4*)(p + (size_t)pp * pStride + off);
    v0 += b2f(a.x); v1 += b2f(a.y); v2 += b2f(a.z); v3 += b2f(a.w);
  }
  float4 bs = *(const float4*)(bias + col);
  v0 += bs.x; v1 += bs.y; v2 += bs.z; v3 += bs.w;
  if (RESID) {
    float4 r = *(const float4*)(resid + off);
    v0 += r.x; v1 += r.y; v2 += r.z; v3 += r.w;
  }
  if (!FINAL) *(float4*)(hOut + off) = make_float4(v0, v1, v2, v3);
  float s = v0 + v1 + v2 + v3;
  float q = v0 * v0 + v1 * v1 + v2 * v2 + v3 * v3;
  for (int o2 = 32; o2; o2 >>= 1) { s += __shfl_xor(s, o2); q += __shfl_xor(q, o2); }
  if ((tid & 63) == 0) { red[tid >> 6] = s; red[4 + (tid >> 6)] = q; }
  __syncthreads();
  float ts = red[0] + red[1] + red[2] + red[3];
  float tq = red[4] + red[5] + red[6] + red[7];
  float mu = ts * (1.0f / HID);
  float var = tq * (1.0f / HID) - mu * mu;
  float rs = rsqrtf(var + 1e-6f);
  float o0 = (v0 - mu) * rs * g[col + 0] + b[col + 0];
  float o1 = (v1 - mu) * rs * g[col + 1] + b[col + 1];
  float o2 = (v2 - mu) * rs * g[col + 2] + b[col + 2];
  float o3 = (v3 - mu) * rs * g[col + 3] + b[col + 3];
  if (FINAL) {
    *(float4*)(fOut + off) = make_float4(o0, o1, o2, o3);
  } else {
    *(ushort4*)(xnOut + off) = make_ushort4(f2b(o0), f2b(o1), f2b(o2), f2b(o3));
  }
}

// ---------------- QKV prep: RoPE(q,k)+scale -> head-major; V -> per-head transposed ----
// NOTE: attention scale folds log2(e): scores in log2-space, softmax uses exp2.
__global__ __launch_bounds__(256) void qkvprep_k(const unsigned short* __restrict__ qkvb,
                                                 unsigned short* __restrict__ Qh,
                                                 unsigned short* __restrict__ Kh,
                                                 unsigned short* __restrict__ VT) {
  __shared__ unsigned short Vs[64 * 72];
  const int tile = blockIdx.x, bh = blockIdx.y;
  const int b = bh >> 4, head = bh & 15;
  const int tid = threadIdx.x;
  const int tl = tid >> 2, dc = tid & 3;
  const int tg = tile * 64 + tl;
  const int trc = tg < NTOK ? tg : NTOK - 1;
  const bool valid = tg < NTOK;
  const size_t srow = ((size_t)(b * NTOK + trc)) * 3072 + head * 64 + dc * 16;

  // V chunk -> LDS
  {
    uint4 v0 = *(const uint4*)(qkvb + srow + 2048);
    uint4 v1 = *(const uint4*)(qkvb + srow + 2048 + 8);
    *(uint4*)&Vs[tl * 72 + dc * 16] = v0;
    *(uint4*)&Vs[tl * 72 + dc * 16 + 8] = v1;
  }

  // RoPE on q,k (8 pairs per thread)
  const int t = trc;
  const int dpos = t / 196, rem = t - dpos * 196, hpos = rem / 14, wpos = rem - hpos * 14;
  const float LG = 0.9210340371976184f;  // ln(10000)/10
  union V16 { uint4 u[2]; unsigned short s[16]; };
  V16 qin, kin, qout, kout;
  qin.u[0] = *(const uint4*)(qkvb + srow);
  qin.u[1] = *(const uint4*)(qkvb + srow + 8);
  kin.u[0] = *(const uint4*)(qkvb + srow + 1024);
  kin.u[1] = *(const uint4*)(qkvb + srow + 1024 + 8);
#pragma unroll
  for (int p = 0; p < 8; ++p) {
    int d0 = dc * 16 + 2 * p;
    float qx0 = b2f(qin.s[2 * p]), qx1 = b2f(qin.s[2 * p + 1]);
    float kx0 = b2f(kin.s[2 * p]), kx1 = b2f(kin.s[2 * p + 1]);
    float qo0, qo1, ko0, ko1;
    if (d0 >= 60) { qo0 = qx0; qo1 = qx1; ko0 = kx0; ko1 = kx1; }
    else {
      int region = d0 / 20;
      int j0 = d0 - region * 20;
      int pos = region == 0 ? dpos : (region == 1 ? hpos : wpos);
      float fp = (float)pos;
      int i0 = j0 % 10, i1 = (j0 + 1) % 10;
      float f0 = expf(-LG * (float)i0) * fp;
      float f1 = expf(-LG * (float)i1) * fp;
      float c0 = cosf(f0), s0 = sinf(f0), c1 = cosf(f1), s1 = sinf(f1);
      qo0 = qx0 * c0 - qx1 * s0; qo1 = qx1 * c1 + qx0 * s1;
      ko0 = kx0 * c0 - kx1 * s0; ko1 = kx1 * c1 + kx0 * s1;
    }
    // fold attention scale (1/8) AND log2(e) into Q: scores in log2-space
    const float QS = 0.18033688011112042f;   // 0.125 * log2(e)
    qout.s[2 * p]     = f2b(qo0 * QS);
    qout.s[2 * p + 1] = f2b(qo1 * QS);
    kout.s[2 * p]     = f2b(ko0);
    kout.s[2 * p + 1] = f2b(ko1);
  }
  if (valid) {
    size_t drow = ((size_t)bh * NTOK + tg) * 64 + dc * 16;
    *(uint4*)(Qh + drow)     = qout.u[0];
    *(uint4*)(Qh + drow + 8) = qout.u[1];
    *(uint4*)(Kh + drow)     = kout.u[0];
    *(uint4*)(Kh + drow + 8) = kout.u[1];
  }
  __syncthreads();
  // V transpose out: thread = (dim, token-chunk)
  {
    int d = tid >> 2, tc = tid & 3;
    if (tile * 64 + tc * 16 < NTOK) {
      V16 o;
#pragma unroll
      for (int jj = 0; jj < 16; ++jj) o.s[jj] = Vs[(tc * 16 + jj) * 72 + d];
      unsigned short* dst = VT + ((size_t)bh * 64 + d) * NTOK + tile * 64 + tc * 16;
      *(uint4*)dst = o.u[0];
      *(uint4*)(dst + 8) = o.u[1];
    }
  }
}

// softmax block for one q-group: row-max -> defer-max rescale -> exp2 -> row-sum ->
// pack to bf16 + shfl-redistribute into the two PV B-fragments.
#define SM_BLOCK(S, MREG, LREG, OACC, PF)                                        \
  {                                                                              \
    float rmax = S[0][0];                                                        \
    _Pragma("unroll") for (int nt = 0; nt < 4; ++nt)                             \
      _Pragma("unroll") for (int rr = 0; rr < 4; ++rr)                           \
        rmax = fmaxf(rmax, S[nt][rr]);                                           \
    rmax = fmaxf(rmax, __shfl_xor(rmax, 16));                                    \
    rmax = fmaxf(rmax, __shfl_xor(rmax, 32));                                    \
    if (!__all(rmax - MREG <= 11.5f)) {                                          \
      float mn = fmaxf(MREG, rmax);                                              \
      float alpha = e2(MREG - mn);                                               \
      MREG = mn;                                                                 \
      LREG *= alpha;                                                             \
      _Pragma("unroll") for (int dt = 0; dt < 4; ++dt)                           \
        _Pragma("unroll") for (int rr = 0; rr < 4; ++rr) OACC[dt][rr] *= alpha;  \
    }                                                                            \
    float rsum = 0.0f;                                                           \
    _Pragma("unroll") for (int nt = 0; nt < 4; ++nt)                             \
      _Pragma("unroll") for (int rr = 0; rr < 4; ++rr) {                         \
        float pv = e2(S[nt][rr] - MREG);                                         \
        S[nt][rr] = pv;                                                          \
        rsum += pv;                                                              \
      }                                                                          \
    rsum += __shfl_xor(rsum, 16);                                                \
    rsum += __shfl_xor(rsum, 32);                                                \
    LREG += rsum;                                                                \
    unsigned pk01[4], pk23[4];                                                   \
    _Pragma("unroll") for (int nt = 0; nt < 4; ++nt) {                           \
      pk01[nt] = cvt2(S[nt][0], S[nt][1]);                                       \
      pk23[nt] = cvt2(S[nt][2], S[nt][3]);                                       \
    }                                                                            \
    _Pragma("unroll") for (int kc = 0; kc < 2; ++kc) {                           \
      unsigned t0, t1;                                                           \
      t0 = __shfl(pk01[2 * kc], srcA); t1 = __shfl(pk01[2 * kc + 1], srcA);      \
      PF[kc].u[0] = hi ? t1 : t0;                                                \
      t0 = __shfl(pk23[2 * kc], srcA); t1 = __shfl(pk23[2 * kc + 1], srcA);      \
      PF[kc].u[1] = hi ? t1 : t0;                                                \
      t0 = __shfl(pk01[2 * kc], srcB); t1 = __shfl(pk01[2 * kc + 1], srcB);      \
      PF[kc].u[2] = hi ? t1 : t0;                                                \
      t0 = __shfl(pk23[2 * kc], srcB); t1 = __shfl(pk23[2 * kc + 1], srcB);      \
      PF[kc].u[3] = hi ? t1 : t0;                                                \
    }                                                                            \
  }

// ---------------- flash attention v8: QBLK=128 + counted-vmcnt tri-buffer ------------
// grid (32 bh, 13 q-tiles, 2 kv). Tri-buffered K/V LDS (48 KB), stage-ahead-2,
// vmcnt(4) counted gate (never drains mid-loop). Ledger: at top of kt, outstanding =
// tile kt+1 (4 loads); vmcnt(4) retires tile kt; barrier -> chip-wide. Stage target
// buf (c+2)%3 was last read at kt-1, freed by current barrier.
__global__ __launch_bounds__(256, 3) void flash6_k(const unsigned short* __restrict__ Qh,
                                                   const unsigned short* __restrict__ Kh,
                                                   const unsigned short* __restrict__ VT,
                                                   unsigned short* __restrict__ Opart,
                                                   float2* __restrict__ ml) {
  __shared__ unsigned short Ks[3][64 * 64];
  __shared__ unsigned short Vs[3][64 * 64];
  const int bh = blockIdx.x, qt = blockIdx.y, kv = blockIdx.z;
  const int kt0 = kv ? 13 : 0, kt1 = kv ? 25 : 13;
  const int tid = threadIdx.x, lane = tid & 63, w = tid >> 6;
  const int l15 = lane & 15, l4 = lane >> 4;
  const size_t hb = (size_t)bh * NTOK * 64;
  const unsigned short* kgp = Kh + hb;
  const unsigned short* vbp = VT + (size_t)bh * 64 * NTOK;

  const int srow0 = w * 8 + (lane >> 3);          // it=0 row
  const int scg0  = (lane & 7) ^ (srow0 & 7);
  const int srow1 = srow0 + 32;                   // it=1 row
  const int scg1  = (lane & 7) ^ (srow1 & 7);

  auto stage = [&](int buf, int kc) {
    async16(kgp + (size_t)(kc + srow0) * 64 + scg0 * 8, &Ks[buf][(size_t)w * 512]);
    async16(kgp + (size_t)(kc + srow1) * 64 + scg1 * 8, &Ks[buf][(size_t)(w + 4) * 512]);
    async16(vbp + (size_t)srow0 * NTOK + kc + scg0 * 8, &Vs[buf][(size_t)w * 512]);
    async16(vbp + (size_t)srow1 * NTOK + kc + scg1 * 8, &Vs[buf][(size_t)(w + 4) * 512]);
  };

  // two q-groups of 16 rows each per wave
  const int qrow0 = qt * 128 + w * 32 + l15;
  const int qrow1 = qrow0 + 16;
  const int qrc0 = qrow0 < NTOK ? qrow0 : NTOK - 1;
  const int qrc1 = qrow1 < NTOK ? qrow1 : NTOK - 1;
  bf16x8 qa0 = *(const bf16x8*)(Qh + hb + (size_t)qrc0 * 64 + l4 * 8);
  bf16x8 qa1 = *(const bf16x8*)(Qh + hb + (size_t)qrc0 * 64 + 32 + l4 * 8);
  bf16x8 qb0 = *(const bf16x8*)(Qh + hb + (size_t)qrc1 * 64 + l4 * 8);
  bf16x8 qb1 = *(const bf16x8*)(Qh + hb + (size_t)qrc1 * 64 + 32 + l4 * 8);

  f32x4 oaccA[4] = {}, oaccB[4] = {};
  float mA = -1e30f, lA = 0.0f, mB = -1e30f, lB = 0.0f;

  // prologue: stage tiles kt0, kt0+1
  stage(0, kt0 * 64);
  stage(1, (kt0 + 1) * 64);

  const int h7 = l15 & 7;
  const int p1 = (l4 ^ h7) * 8;          // phys offset of logical chunk l4
  const int p2 = ((l4 + 4) ^ h7) * 8;    // phys offset of logical chunk l4+4
  const int srcA = ((l4 & 1) << 5) | l15;
  const int srcB = srcA + 16;
  const bool hi = (l4 >> 1) != 0;

  int cur = 0;
  for (int kt = kt0; kt < kt1; ++kt) {
    const int kb = kt * 64;
    // counted gate: retire tile kt (tile kt+1 stays in flight)
    if (kt + 1 < kt1) {
      asm volatile("s_waitcnt vmcnt(4)" ::: "memory");
    } else {
      asm volatile("s_waitcnt vmcnt(0)" ::: "memory");
    }
    __builtin_amdgcn_s_barrier();
    __builtin_amdgcn_sched_barrier(0);   // ds_reads must not hoist above barrier
    if (kt + 2 < kt1) {
      int nxt2 = cur + 2; if (nxt2 >= 3) nxt2 -= 3;
      stage(nxt2, (kt + 2) * 64);
    }

    bf16x8 kc0[4], kc1[4];
#pragma unroll
    for (int nt = 0; nt < 4; ++nt) {
      const unsigned short* kr = &Ks[cur][(nt * 16 + l15) * 64];
      kc0[nt] = *(const bf16x8*)(kr + p1);
      kc1[nt] = *(const bf16x8*)(kr + p2);
    }
    f32x4 sA[4] = {}, sB[4] = {};
    __builtin_amdgcn_s_setprio(1);
#pragma unroll
    for (int nt = 0; nt < 4; ++nt) {
      sA[nt] = __builtin_amdgcn_mfma_f32_16x16x32_bf16(kc0[nt], qa0, sA[nt], 0, 0, 0);
      sA[nt] = __builtin_amdgcn_mfma_f32_16x16x32_bf16(kc1[nt], qa1, sA[nt], 0, 0, 0);
      sB[nt] = __builtin_amdgcn_mfma_f32_16x16x32_bf16(kc0[nt], qb0, sB[nt], 0, 0, 0);
      sB[nt] = __builtin_amdgcn_mfma_f32_16x16x32_bf16(kc1[nt], qb1, sB[nt], 0, 0, 0);
    }
    __builtin_amdgcn_s_setprio(0);
    bf16x8 vf0[4], vf1[4];
#pragma unroll
    for (int dt = 0; dt < 4; ++dt) {
      const unsigned short* vr = &Vs[cur][(dt * 16 + l15) * 64];
      vf0[dt] = *(const bf16x8*)(vr + p1);
      vf1[dt] = *(const bf16x8*)(vr + p2);
    }

    if (kb + 64 > NTOK) {
#pragma unroll
      for (int nt = 0; nt < 4; ++nt)
#pragma unroll
        for (int rr = 0; rr < 4; ++rr)
          if (kb + nt * 16 + l4 * 4 + rr >= NTOK) { sA[nt][rr] = -1e30f; sB[nt][rr] = -1e30f; }
    }

    union PB { unsigned u[4]; bf16x8 v; } pfA[2], pfB[2];
    SM_BLOCK(sA, mA, lA, oaccA, pfA)
    __builtin_amdgcn_s_setprio(1);
#pragma unroll
    for (int dt = 0; dt < 4; ++dt) {
      oaccA[dt] = __builtin_amdgcn_mfma_f32_16x16x32_bf16(vf0[dt], pfA[0].v, oaccA[dt], 0, 0, 0);
      oaccA[dt] = __builtin_amdgcn_mfma_f32_16x16x32_bf16(vf1[dt], pfA[1].v, oaccA[dt], 0, 0, 0);
    }
    __builtin_amdgcn_s_setprio(0);
    SM_BLOCK(sB, mB, lB, oaccB, pfB)
    __builtin_amdgcn_s_setprio(1);
#pragma unroll
    for (int dt = 0; dt < 4; ++dt) {
      oaccB[dt] = __builtin_amdgcn_mfma_f32_16x16x32_bf16(vf0[dt], pfB[0].v, oaccB[dt], 0, 0, 0);
      oaccB[dt] = __builtin_amdgcn_mfma_f32_16x16x32_bf16(vf1[dt], pfB[1].v, oaccB[dt], 0, 0, 0);
    }
    __builtin_amdgcn_s_setprio(0);
    cur = cur + 1 == 3 ? 0 : cur + 1;
  }

  // epilogue: per q-group O~^T -> LDS transpose (per-wave private region, aliased
  // into Ks after barrier) -> bf16 partial. Same-wave ds write->read, in-order.
  __syncthreads();                          // full drain: all waves done with Ks/Vs
  unsigned short* Os = &Ks[0][0];           // 4 waves * 1152 ushorts < 12288
#pragma unroll
  for (int dt = 0; dt < 4; ++dt)
#pragma unroll
    for (int rr = 0; rr < 4; ++rr)
      Os[w * 1152 + l15 * 72 + dt * 16 + l4 * 4 + rr] = f2b(oaccA[dt][rr]);
  if (qrow0 < NTOK) {
    uint4 a  = *(const uint4*)&Os[w * 1152 + l15 * 72 + l4 * 16];
    uint4 bq = *(const uint4*)&Os[w * 1152 + l15 * 72 + l4 * 16 + 8];
    unsigned short* op = Opart + ((size_t)(kv * 32 + bh) * NTOK + qrow0) * 64;
    *(uint4*)(op + l4 * 16) = a;
    *(uint4*)(op + l4 * 16 + 8) = bq;
    if (l4 == 0) ml[(size_t)(kv * 32 + bh) * NTOK + qrow0] = make_float2(mA, lA);
  }
  __builtin_amdgcn_sched_barrier(0);        // keep qg=0 reads before qg=1 writes
#pragma unroll
  for (int dt = 0; dt < 4; ++dt)
#pragma unroll
    for (int rr = 0; rr < 4; ++rr)
      Os[w * 1152 + l15 * 72 + dt * 16 + l4 * 4 + rr] = f2b(oaccB[dt][rr]);
  if (qrow1 < NTOK) {
    uint4 a  = *(const uint4*)&Os[w * 1152 + l15 * 72 + l4 * 16];
    uint4 bq = *(const uint4*)&Os[w * 1152 + l15 * 72 + l4 * 16 + 8];
    unsigned short* op = Opart + ((size_t)(kv * 32 + bh) * NTOK + qrow1) * 64;
    *(uint4*)(op + l4 * 16) = a;
    *(uint4*)(op + l4 * 16 + 8) = bq;
    if (l4 == 0) ml[(size_t)(kv * 32 + bh) * NTOK + qrow1] = make_float2(mB, lB);
  }
}

// ---------------- combine the two KV-split partials -> ob ----------------------------
__global__ __launch_bounds__(256) void fcomb_k(const unsigned short* __restrict__ Op,
                                               const float2* __restrict__ ml,
                                               unsigned short* __restrict__ O) {
  const int bh = blockIdx.x, qt = blockIdx.y;
  const int tid = threadIdx.x;
  const int qr = qt * 64 + (tid >> 2);
  const int dc = (tid & 3) * 16;
  if (qr >= NTOK) return;
  const int b = bh >> 4, head = bh & 15;
  float2 a0 = ml[(size_t)bh * NTOK + qr];          // kv=0: (m, l)
  float2 a1 = ml[(size_t)(32 + bh) * NTOK + qr];   // kv=1
  float M = fmaxf(a0.x, a1.x);
  float w0 = e2(a0.x - M), w1 = e2(a1.x - M);
  float inv = 1.0f / (a0.y * w0 + a1.y * w1);
  w0 *= inv; w1 *= inv;
  union V16 { uint4 u[2]; unsigned short s[16]; } p0, p1, o;
  const unsigned short* q0 = Op + ((size_t)bh * NTOK + qr) * 64 + dc;
  const unsigned short* q1 = Op + ((size_t)(32 + bh) * NTOK + qr) * 64 + dc;
  p0.u[0] = *(const uint4*)q0;       p0.u[1] = *(const uint4*)(q0 + 8);
  p1.u[0] = *(const uint4*)q1;       p1.u[1] = *(const uint4*)(q1 + 8);
#pragma unroll
  for (int j = 0; j < 16; ++j) o.s[j] = f2b(b2f(p0.s[j]) * w0 + b2f(p1.s[j]) * w1);
  unsigned short* dst = O + ((size_t)(b * NTOK + qr)) * HID + head * 64 + dc;
  *(uint4*)dst = o.u[0];
  *(uint4*)(dst + 8) = o.u[1];
}

// ---------------- host launch ----------------
extern "C" void kernel_launch(void* const* d_in, const int* in_sizes, int n_in,
                              void* d_out, int out_size, void* d_ws, size_t ws_size,
                              hipStream_t stream) {
  (void)in_sizes; (void)n_in; (void)out_size; (void)ws_size;
  const float* pv      = (const float*)d_in[0];
  const float* patch_w = (const float*)d_in[1];
  const float* patch_b = (const float*)d_in[2];
  const float* ln1_g   = (const float*)d_in[3];
  const float* ln1_b   = (const float*)d_in[4];
  const float* qw = (const float*)d_in[5];
  const float* qb = (const float*)d_in[6];
  const float* kw = (const float*)d_in[7];
  const float* kb = (const float*)d_in[8];
  const float* vw = (const float*)d_in[9];
  const float* vb = (const float*)d_in[10];
  const float* pw = (const float*)d_in[11];
  const float* pb = (const float*)d_in[12];
  const float* ln2_g = (const float*)d_in[13];
  const float* ln2_b = (const float*)d_in[14];
  const float* fc1w = (const float*)d_in[15];
  const float* fc1b = (const float*)d_in[16];
  const float* fc2w = (const float*)d_in[17];
  const float* fc2b = (const float*)d_in[18];
  const float* lnf_g = (const float*)d_in[19];
  const float* lnf_b = (const float*)d_in[20];

  char* wsp = (char*)d_ws;
  auto alloc = [&](size_t bytes) {
    char* p = wsp;
    wsp += (bytes + 255) & ~(size_t)255;
    return p;
  };
  unsigned short* wPatch = (unsigned short*)alloc((size_t)1024 * 1536 * 2);
  unsigned short* wQKV   = (unsigned short*)alloc((size_t)NLAYER * 3072 * 1024 * 2);
  unsigned short* wP     = (unsigned short*)alloc((size_t)NLAYER * HID * HID * 2);
  unsigned short* wF1    = (unsigned short*)alloc((size_t)NLAYER * MLPD * HID * 2);
  unsigned short* wF2    = (unsigned short*)alloc((size_t)NLAYER * HID * MLPD * 2);
  float*          qkvbias = (float*)alloc((size_t)NLAYER * 3072 * 4);
  unsigned short* Aim  = (unsigned short*)alloc((size_t)ROWS * CONVK * 2);
  float*          h    = (float*)alloc((size_t)ROWS * HID * 4);
  unsigned short* xnb  = (unsigned short*)alloc((size_t)ROWS * HID * 2);
  unsigned short* qkvo = (unsigned short*)alloc((size_t)ROWS * 3072 * 2);
  unsigned short* Qh   = (unsigned short*)alloc((size_t)ROWS * HID * 2 + 8192);
  unsigned short* Kh   = (unsigned short*)alloc((size_t)ROWS * HID * 2 + 8192);
  unsigned short* VT   = (unsigned short*)alloc((size_t)ROWS * HID * 2 + 8192);
  unsigned short* ob   = (unsigned short*)alloc((size_t)ROWS * HID * 2);
  unsigned short* mb   = (unsigned short*)alloc((size_t)ROWS * MLPD * 2);

  // Aliasing plan (all stream-ordered):
  //  part  (=Qh): conv z0..3 (25.7MB spans Qh..ob, consumed by redln before qkvprep),
  //               fc2 z0..3 (same span; consumed before next-layer writes).
  //  partM (=mb): proj z0..3 (ob is proj's A, partials must NOT hit ob).
  //  Opart/ml (=mb): flash partials, consumed by fcomb before proj overwrites mb.
  //  qkv + fc1 are single-z with fused bias(+gelu) epilogues: write final outputs
  //  (qkvo / mb) directly -- no partial buffers, no reduce pass.
  unsigned short* part  = Qh;
  unsigned short* partM = mb;
  unsigned short* Opart = mb;
  float2*         mlbuf = (float2*)(mb + (size_t)2 * 32 * NTOK * 64);
  const size_t MNs = (size_t)ROWS * HID;

  auto cast = [&](const float* s, unsigned short* d, long long n) {
    long long n4 = n / 4;
    int grid = (int)((n4 + 255) / 256);
    if (grid > 16384) grid = 16384;
    cast4_k<<<grid, 256, 0, stream>>>(s, d, n4);
  };
  cast(patch_w, wPatch, (long long)1024 * 1536);
  castqkv_k<<<dim3(4096, 3), 256, 0, stream>>>(qw, kw, vw, wQKV);
  cast(pw, wP, (long long)NLAYER * HID * HID);
  cast(fc1w, wF1, (long long)NLAYER * MLPD * HID);
  cast(fc2w, wF2, (long long)NLAYER * HID * MLPD);
  biascat_k<<<48, 256, 0, stream>>>(qb, kb, vb, qkvbias);

  im2col_k<<<(ROWS * CONVK) / 256, 256, 0, stream>>>(pv, Aim);
  // conv GEMM split-K x4 (kChunk 384) -> h = sum+bias, xnb = LN1_0(h)
  gemm256<0><<<dim3(4, 13, 4), 512, 0, stream>>>(
      Aim, wPatch, part, ROWS, HID, CONVK, 384, MNs, nullptr);
  redln_k<4, 0, 0><<<ROWS, 256, 0, stream>>>(
      part, patch_b, nullptr, ln1_g, ln1_b, h, xnb, nullptr, MNs);

  for (int i = 0; i < NLAYER; ++i) {
    // qkv: single-K GEMM with fused bias -> qkvo directly
    gemm256<1><<<dim3(12, 13, 1), 512, 0, stream>>>(
        xnb, wQKV + (size_t)i * 3072 * 1024, qkvo, ROWS, 3072, HID, 1024,
        0, qkvbias + i * 3072);
    qkvprep_k<<<dim3(25, 32), 256, 0, stream>>>(qkvo, Qh, Kh, VT);
    flash6_k<<<dim3(32, 13, 2), 256, 0, stream>>>(Qh, Kh, VT, Opart, mlbuf);
    fcomb_k<<<dim3(32, 25), 256, 0, stream>>>(Opart, mlbuf, ob);
    // proj split-K x4 (kChunk 256; partials in mb, NOT ob) -> h += proj+pb, xnb = LN2(h)
    gemm256<0><<<dim3(4, 13, 4), 512, 0, stream>>>(
        ob, wP + (size_t)i * HID * HID, partM, ROWS, HID, HID, 256, MNs, nullptr);
    redln_k<4, 1, 0><<<ROWS, 256, 0, stream>>>(
        partM, pb + i * HID, h, ln2_g + i * HID, ln2_b + i * HID, h, xnb, nullptr, MNs);
    // fc1: single-K GEMM with fused bias+gelu -> mb directly
    gemm256<2><<<dim3(16, 13, 1), 512, 0, stream>>>(
        xnb, wF1 + (size_t)i * MLPD * HID, mb, ROWS, MLPD, HID, 1024,
        0, fc1b + i * MLPD);
    // fc2 split-K x4 (kChunk 1024) -> h += fc2+bias, then LN1(next) or LNf->out
    gemm256<0><<<dim3(4, 13, 4), 512, 0, stream>>>(
        mb, wF2 + (size_t)i * HID * MLPD, part, ROWS, HID, MLPD, 1024, MNs, nullptr);
    if (i < NLAYER - 1) {
      redln_k<4, 1, 0><<<ROWS, 256, 0, stream>>>(
          part, fc2b + i * HID, h, ln1_g + (i + 1) * HID, ln1_b + (i + 1) * HID,
          h, xnb, nullptr, MNs);
    } else {
      redln_k<4, 1, 1><<<ROWS, 256, 0, stream>>>(
          part, fc2b + i * HID, h, lnf_g, lnf_b, nullptr, nullptr, (float*)d_out, MNs);
    }
  }
}

// Round 7
// 1274.483 us; speedup vs baseline: 1.0360x; 1.0360x over previous
//
#include <hip/hip_runtime.h>
#include <math.h>

// ---------------- constants ----------------
#define NTOK   1568
#define BATCH  2
#define HID    1024
#define MLPD   4096
#define NLAYER 4
#define ROWS   (BATCH*NTOK)   // 3136
#define CONVK  1536

typedef __bf16 bf16x8 __attribute__((ext_vector_type(8)));
typedef __bf16 bf16x2 __attribute__((ext_vector_type(2)));
typedef float  f32x4  __attribute__((ext_vector_type(4)));

__device__ __forceinline__ unsigned short f2b(float f) {
  unsigned int u = __float_as_uint(f);
  unsigned int r = u + 0x7FFFu + ((u >> 16) & 1u);   // RNE
  return (unsigned short)(r >> 16);
}
__device__ __forceinline__ float b2f(unsigned short s) {
  return __uint_as_float((unsigned int)s << 16);
}
// packed f32->bf16 pair via native casts (gfx950: v_cvt_pk_bf16_f32)
__device__ __forceinline__ unsigned cvt2(float a, float b) {
  bf16x2 t;
  t[0] = (__bf16)a;
  t[1] = (__bf16)b;
  return __builtin_bit_cast(unsigned, t);
}
__device__ __forceinline__ float e2(float x) { return __builtin_amdgcn_exp2f(x); }

// async global->LDS 16B; lds ptr must be wave-uniform base (HW adds lane*16)
__device__ __forceinline__ void async16(const unsigned short* g, unsigned short* l) {
  __builtin_amdgcn_global_load_lds(
      (__attribute__((address_space(1))) void*)(void*)g,
      (__attribute__((address_space(3))) void*)(void*)l, 16, 0, 0);
}

// ---------------- fp32 -> bf16 cast (x4 vectorized, grid-stride) ----------------
__global__ __launch_bounds__(256) void cast4_k(const float* __restrict__ s,
                                               unsigned short* __restrict__ d,
                                               long long n4) {
  long long i = (long long)blockIdx.x * 256 + threadIdx.x;
  long long stride = (long long)gridDim.x * 256;
  for (; i < n4; i += stride) {
    float4 v = ((const float4*)s)[i];
    *(ushort4*)(d + i * 4) = make_ushort4(f2b(v.x), f2b(v.y), f2b(v.z), f2b(v.w));
  }
}

// cast q/k/v weights into one concatenated per-layer buffer wQKV[L][3072][1024]
__global__ __launch_bounds__(256) void castqkv_k(const float* __restrict__ q,
                                                 const float* __restrict__ k,
                                                 const float* __restrict__ v,
                                                 unsigned short* __restrict__ dst) {
  const float* src = blockIdx.y == 0 ? q : (blockIdx.y == 1 ? k : v);
  long long i4 = (long long)blockIdx.x * 256 + threadIdx.x;   // exactly L*HH/4
  long long e = i4 * 4;
  int layer = (int)(e >> 20);                                  // HH = 1<<20
  long long de = e + ((long long)(2 * layer + blockIdx.y) << 20);
  float4 val = ((const float4*)src)[i4];
  *(ushort4*)(dst + de) = make_ushort4(f2b(val.x), f2b(val.y), f2b(val.z), f2b(val.w));
}

__global__ __launch_bounds__(256) void biascat_k(const float* __restrict__ qb,
                                                 const float* __restrict__ kb,
                                                 const float* __restrict__ vb,
                                                 float* __restrict__ dst) {
  int idx = blockIdx.x * 256 + threadIdx.x;   // L*3072
  int layer = idx / 3072, c = idx % 3072;
  float v = c < 1024 ? qb[layer * 1024 + c]
            : (c < 2048 ? kb[layer * 1024 + c - 1024] : vb[layer * 1024 + c - 2048]);
  dst[idx] = v;
}

// ---------------- im2col for the tubelet conv ----------------
__global__ __launch_bounds__(256) void im2col_k(const float* __restrict__ pv,
                                                unsigned short* __restrict__ A) {
  int idx = blockIdx.x * 256 + threadIdx.x;       // exactly ROWS*CONVK threads
  int row = idx / CONVK, col = idx % CONVK;
  int b = row / NTOK, t = row % NTOK;
  int d = t / 196, r = t % 196, hh = r / 14, ww = r % 14;
  int c = col >> 9, r2 = col & 511, td = r2 >> 8, ph = (r2 >> 4) & 15, pw = r2 & 15;
  int frame = 2 * d + td;
  const float* src = pv + ((((long long)b * 16 + frame) * 3 + c) * 224 + (hh * 16 + ph)) * 224
                        + (ww * 16 + pw);
  A[idx] = f2b(*src);
}

// ---------------- GEMM v6: 256x256 tile, 8 waves, BK=64, TRUE 8-phase schedule ------
// out[z][M,N] = A[M,K_z](bf16) * B[N,K_z]^T(bf16). EPI: 0 raw, 1 +bias, 2 +bias+gelu.
// m201-style schedule (T3+T4): per K-tile (BK=64), 4 quadrant-phases, each
//   { ds_read subtile | issue 1 half-tile stage | s_barrier | setprio(1) 16 MFMA
//     setprio(0) | counted vmcnt gate | s_barrier }.
// Double-buffered LDS (128 KB). Half-tiles staged in FIRST-USE order Ah0,Bh0,Bh1,Ah1
// (Ah = 64-row quarters {h,h+2} so both wr-slabs' quadrant rows land; Bh = 32-row
// stripes matching quadrant nh). Per-wave vmcnt ledger (2 wave-loads per half):
//   end-P4: out={Ah0,Bh0,Bh1,Ah1}'=8 -> vmcnt(4) retires Ah0',Bh0' (P1-next safe)
//   end-P1: out={Bh1,Ah1}+Ah0''=6    -> vmcnt(4) retires Bh1     (P2 safe)
//   end-P2: out={Ah1}+{Ah0,Bh0}''=6  -> vmcnt(4) retires Ah1     (P3 safe)
//   last tile peels to vmcnt(2)/vmcnt(0); never a mid-loop drain.
// Gate BEFORE barrier: each wave proves ITS loads landed, barrier makes all waves'
// deposits visible. sched_barrier(0) after each gated barrier stops ds_read hoist.
// XOR involution swizzle chunk^=(row&7) (8 chunks/row; <=2-way conflict = free) on
// stage-source + ds_read; m204 bijective XCD swizzle.
template <int EPI>
__global__ __launch_bounds__(512, 2) void gemm256(const unsigned short* __restrict__ A,
                                                  const unsigned short* __restrict__ B,
                                                  unsigned short* outP,
                                                  int M, int N, int K, int kChunk,
                                                  size_t zStride,
                                                  const float* __restrict__ bias) {
  __shared__ unsigned short As[2][256 * 64];
  __shared__ unsigned short Bs[2][256 * 64];
  const int tid = threadIdx.x;
  const int lane = tid & 63;
  const int w = tid >> 6;              // 0..7
  const int wr = w >> 2, wc = w & 3;   // wave -> (2 x 4) C sub-tiles of 128x64
  const int l15 = lane & 15, l4 = lane >> 4;

  // XCD-aware bijective remap of the flat workgroup id (T1, m204 formula)
  const int gx = gridDim.x, gy = gridDim.y;
  const int nwg = gx * gy * (int)gridDim.z;
  int orig = blockIdx.x + gx * (blockIdx.y + gy * blockIdx.z);
  int q = nwg >> 3, r = nwg & 7, xcd = orig & 7, idx = orig >> 3;
  int swz = (xcd < r ? xcd * (q + 1) : r * (q + 1) + (xcd - r) * q) + idx;
  const int bn = swz % gx;
  int tmp = swz / gx;
  const int bm = tmp % gy;
  const int bz = tmp / gy;
  const int kbeg = bz * kChunk;

  // ---- staging precompute. Deposit thread i -> LDS row r5=i>>3, phys chunk i&7;
  // stored content at (row,phys p) is logical chunk p^(row&7); row&7 == (i>>3)&7
  // for every line (all line row-bases are multiples of 8) -> global source chunk:
  const int r5 = tid >> 3;                       // 0..63
  const int gc8 = ((tid & 7) ^ (r5 & 7)) * 8;
  // A lines L=0..3 cover tile rows L*64..L*64+63 (clamped M tail)
  int ar0 = bm * 256 + r5;        if (ar0 >= M) ar0 = M - 1;
  int ar1 = bm * 256 + 64 + r5;   if (ar1 >= M) ar1 = M - 1;
  int ar2 = bm * 256 + 128 + r5;  if (ar2 >= M) ar2 = M - 1;
  int ar3 = bm * 256 + 192 + r5;  if (ar3 >= M) ar3 = M - 1;
  const size_t Ao0 = (size_t)ar0 * K + gc8;
  const size_t Ao1 = (size_t)ar1 * K + gc8;
  const size_t Ao2 = (size_t)ar2 * K + gc8;
  const size_t Ao3 = (size_t)ar3 * K + gc8;
  const int aw8 = w * 512;                       // wave-uniform LDS base (ushort)
  // B half nh = stripes {s*64 + nh*32 .. +31, s=0..3}; line (nh,j) covers j*128 rows
  const int q5 = r5 >> 5, r31 = r5 & 31;
  const size_t Bo00 = (size_t)(bn * 256 +       q5 * 64 +      r31) * K + gc8;  // nh0,j0
  const size_t Bo01 = (size_t)(bn * 256 + 128 + q5 * 64 +      r31) * K + gc8;  // nh0,j1
  const size_t Bo10 = (size_t)(bn * 256 +       q5 * 64 + 32 + r31) * K + gc8;  // nh1,j0
  const size_t Bo11 = (size_t)(bn * 256 + 128 + q5 * 64 + 32 + r31) * K + gc8;  // nh1,j1
  const int bwrow = (w >> 2) * 64 + 8 * (w & 3);         // wave-uniform row base
  const int bl00 = (bwrow) * 64;
  const int bl01 = (128 + bwrow) * 64;
  const int bl10 = (32 + bwrow) * 64;
  const int bl11 = (160 + bwrow) * 64;

  auto stAh = [&](int bf, int h, int k0) {
    if (h == 0) {
      async16(A + Ao0 + k0, &As[bf][aw8]);
      async16(A + Ao2 + k0, &As[bf][2 * 4096 + aw8]);
    } else {
      async16(A + Ao1 + k0, &As[bf][1 * 4096 + aw8]);
      async16(A + Ao3 + k0, &As[bf][3 * 4096 + aw8]);
    }
  };
  auto stBh = [&](int bf, int nh, int k0) {
    if (nh == 0) {
      async16(B + Bo00 + k0, &Bs[bf][bl00]);
      async16(B + Bo01 + k0, &Bs[bf][bl01]);
    } else {
      async16(B + Bo10 + k0, &Bs[bf][bl10]);
      async16(B + Bo11 + k0, &Bs[bf][bl11]);
    }
  };

  f32x4 acc[8][4] = {};
  const int nk = kChunk >> 6;          // >= 4 for all our shapes

  // ds_read addressing (swizzled): logical chunk lc = s*4+l4 -> phys lc^(l15&7)
  const int h7 = l15 & 7;
  const int pc0 = (l4 ^ h7) * 8;
  const int pc1 = ((l4 + 4) ^ h7) * 8;
  const int abase = (wr * 128 + l15) * 64;
  const int bbase = (wc * 64 + l15) * 64;

#define READ_A(MH)                                                                 \
  _Pragma("unroll")                                                                \
  for (int mm = 0; mm < 4; ++mm) {                                                 \
    afr[mm][0] = *(const bf16x8*)&As[cur][abase + ((MH) * 64 + mm * 16) * 64 + pc0]; \
    afr[mm][1] = *(const bf16x8*)&As[cur][abase + ((MH) * 64 + mm * 16) * 64 + pc1]; \
  }
#define READ_B(NH)                                                                 \
  _Pragma("unroll")                                                                \
  for (int nn = 0; nn < 2; ++nn) {                                                 \
    bfr[NH][nn][0] = *(const bf16x8*)&Bs[cur][bbase + ((NH) * 32 + nn * 16) * 64 + pc0]; \
    bfr[NH][nn][1] = *(const bf16x8*)&Bs[cur][bbase + ((NH) * 32 + nn * 16) * 64 + pc1]; \
  }
#define QUAD(MH, NH)                                                               \
  _Pragma("unroll")                                                                \
  for (int mm = 0; mm < 4; ++mm) {                                                 \
    _Pragma("unroll")                                                              \
    for (int nn = 0; nn < 2; ++nn) {                                               \
      acc[(MH)*4+mm][(NH)*2+nn] = __builtin_amdgcn_mfma_f32_16x16x32_bf16(         \
          afr[mm][0], bfr[NH][nn][0], acc[(MH)*4+mm][(NH)*2+nn], 0, 0, 0);         \
      acc[(MH)*4+mm][(NH)*2+nn] = __builtin_amdgcn_mfma_f32_16x16x32_bf16(         \
          afr[mm][1], bfr[NH][nn][1], acc[(MH)*4+mm][(NH)*2+nn], 0, 0, 0);         \
    }                                                                              \
  }

  // prologue: tile 0, first-use order
  stAh(0, 0, kbeg); stBh(0, 0, kbeg); stBh(0, 1, kbeg); stAh(0, 1, kbeg);
  asm volatile("s_waitcnt vmcnt(4)" ::: "memory");
  __builtin_amdgcn_s_barrier();
  __builtin_amdgcn_sched_barrier(0);

  for (int kt = 0; kt < nk; ++kt) {
    const int cur = kt & 1, nxt = cur ^ 1;
    const bool st = (kt + 1 < nk);
    const int kn = kbeg + (kt + 1) * 64;
    bf16x8 afr[4][2], bfr[2][2][2];

    // ---- P1: read A[mh0] + B[nh0] | stage Ah0(next) | bar | MFMA(0,0) | gate | bar
    READ_A(0)
    READ_B(0)
    if (st) stAh(nxt, 0, kn);
    __builtin_amdgcn_s_barrier();
    __builtin_amdgcn_s_setprio(1);
    QUAD(0, 0)
    __builtin_amdgcn_s_setprio(0);
    if (st) { asm volatile("s_waitcnt vmcnt(4)" ::: "memory"); }
    else    { asm volatile("s_waitcnt vmcnt(2)" ::: "memory"); }
    __builtin_amdgcn_s_barrier();
    __builtin_amdgcn_sched_barrier(0);

    // ---- P2: read B[nh1] | stage Bh0(next) | bar | MFMA(0,1) | gate | bar
    READ_B(1)
    if (st) stBh(nxt, 0, kn);
    __builtin_amdgcn_s_barrier();
    __builtin_amdgcn_s_setprio(1);
    QUAD(0, 1)
    __builtin_amdgcn_s_setprio(0);
    if (st) { asm volatile("s_waitcnt vmcnt(4)" ::: "memory"); }
    else    { asm volatile("s_waitcnt vmcnt(0)" ::: "memory"); }
    __builtin_amdgcn_s_barrier();
    __builtin_amdgcn_sched_barrier(0);

    // ---- P3: read A[mh1] | stage Bh1(next) | bar | MFMA(1,1) | bar
    READ_A(1)
    if (st) stBh(nxt, 1, kn);
    __builtin_amdgcn_s_barrier();
    __builtin_amdgcn_s_setprio(1);
    QUAD(1, 1)
    __builtin_amdgcn_s_setprio(0);
    __builtin_amdgcn_s_barrier();

    // ---- P4: stage Ah1(next) | bar | MFMA(1,0) | gate | bar
    if (st) stAh(nxt, 1, kn);
    __builtin_amdgcn_s_barrier();
    __builtin_amdgcn_s_setprio(1);
    QUAD(1, 0)
    __builtin_amdgcn_s_setprio(0);
    if (st) { asm volatile("s_waitcnt vmcnt(4)" ::: "memory"); }
    __builtin_amdgcn_s_barrier();
    __builtin_amdgcn_sched_barrier(0);
  }
#undef READ_A
#undef READ_B
#undef QUAD

  // epilogue. acc[m][n]: row = wr*128 + (m>>2)*64 + (m&3)*16 + l4*4 + reg;
  //                      col = wc*64 + (n>>1)*32 + (n&1)*16 + l15
  float bsv[4] = {0, 0, 0, 0};
  if (EPI >= 1) {
#pragma unroll
    for (int n = 0; n < 4; ++n)
      bsv[n] = bias[bn * 256 + wc * 64 + (n >> 1) * 32 + (n & 1) * 16 + l15];
  }
  unsigned short* pout = outP + (size_t)bz * zStride;
#pragma unroll
  for (int m = 0; m < 8; ++m) {
    int rowb = bm * 256 + wr * 128 + (m >> 2) * 64 + (m & 3) * 16 + l4 * 4;
#pragma unroll
    for (int rr2 = 0; rr2 < 4; ++rr2) {
      int rr = rowb + rr2;
      if (rr >= M) continue;
#pragma unroll
      for (int n = 0; n < 4; ++n) {
        int col = bn * 256 + wc * 64 + (n >> 1) * 32 + (n & 1) * 16 + l15;
        float v = acc[m][n][rr2];
        if (EPI >= 1) v += bsv[n];
        if (EPI == 2) v = 0.5f * v * (1.0f + erff(v * 0.70710678118654752f));
        pout[(size_t)rr * N + col] = f2b(v);
      }
    }
  }
}

// ---------------- fused split-K reduce + residual + LayerNorm ------------------------
template <int NP, int RESID, int FINAL>
__global__ __launch_bounds__(256) void redln_k(const unsigned short* __restrict__ p,
                                               const float* __restrict__ bias,
                                               const float* resid,
                                               const float* __restrict__ g,
                                               const float* __restrict__ b,
                                               float* hOut,
                                               unsigned short* __restrict__ xnOut,
                                               float* __restrict__ fOut,
                                               size_t pStride) {
  __shared__ float red[8];
  const int row = blockIdx.x, tid = threadIdx.x;
  const int col = tid * 4;
  const size_t off = (size_t)row * HID + col;
  float v0 = 0, v1 = 0, v2 = 0, v3 = 0;
#pragma unroll
  for (int pp = 0; pp < NP; ++pp) {
    ushort4 a = *(const ushort4*)(p + (size_t)pp * pStride + off);
    v0 += b2f(a.x); v1 += b2f(a.y); v2 += b2f(a.z); v3 += b2f(a.w);
  }
  float4 bs = *(const float4*)(bias + col);
  v0 += bs.x; v1 += bs.y; v2 += bs.z; v3 += bs.w;
  if (RESID) {
    float4 r = *(const float4*)(resid + off);
    v0 += r.x; v1 += r.y; v2 += r.z; v3 += r.w;
  }
  if (!FINAL) *(float4*)(hOut + off) = make_float4(v0, v1, v2, v3);
  float s = v0 + v1 + v2 + v3;
  float q = v0 * v0 + v1 * v1 + v2 * v2 + v3 * v3;
  for (int o2 = 32; o2; o2 >>= 1) { s += __shfl_xor(s, o2); q += __shfl_xor(q, o2); }
  if ((tid & 63) == 0) { red[tid >> 6] = s; red[4 + (tid >> 6)] = q; }
  __syncthreads();
  float ts = red[0] + red[1] + red[2] + red[3];
  float tq = red[4] + red[5] + red[6] + red[7];
  float mu = ts * (1.0f / HID);
  float var = tq * (1.0f / HID) - mu * mu;
  float rs = rsqrtf(var + 1e-6f);
  float o0 = (v0 - mu) * rs * g[col + 0] + b[col + 0];
  float o1 = (v1 - mu) * rs * g[col + 1] + b[col + 1];
  float o2 = (v2 - mu) * rs * g[col + 2] + b[col + 2];
  float o3 = (v3 - mu) * rs * g[col + 3] + b[col + 3];
  if (FINAL) {
    *(float4*)(fOut + off) = make_float4(o0, o1, o2, o3);
  } else {
    *(ushort4*)(xnOut + off) = make_ushort4(f2b(o0), f2b(o1), f2b(o2), f2b(o3));
  }
}

// ---------------- QKV prep: RoPE(q,k)+scale -> head-major; V -> per-head transposed ----
// NOTE: attention scale folds log2(e): scores in log2-space, softmax uses exp2.
__global__ __launch_bounds__(256) void qkvprep_k(const unsigned short* __restrict__ qkvb,
                                                 unsigned short* __restrict__ Qh,
                                                 unsigned short* __restrict__ Kh,
                                                 unsigned short* __restrict__ VT) {
  __shared__ unsigned short Vs[64 * 72];
  const int tile = blockIdx.x, bh = blockIdx.y;
  const int b = bh >> 4, head = bh & 15;
  const int tid = threadIdx.x;
  const int tl = tid >> 2, dc = tid & 3;
  const int tg = tile * 64 + tl;
  const int trc = tg < NTOK ? tg : NTOK - 1;
  const bool valid = tg < NTOK;
  const size_t srow = ((size_t)(b * NTOK + trc)) * 3072 + head * 64 + dc * 16;

  // V chunk -> LDS
  {
    uint4 v0 = *(const uint4*)(qkvb + srow + 2048);
    uint4 v1 = *(const uint4*)(qkvb + srow + 2048 + 8);
    *(uint4*)&Vs[tl * 72 + dc * 16] = v0;
    *(uint4*)&Vs[tl * 72 + dc * 16 + 8] = v1;
  }

  // RoPE on q,k (8 pairs per thread)
  const int t = trc;
  const int dpos = t / 196, rem = t - dpos * 196, hpos = rem / 14, wpos = rem - hpos * 14;
  const float LG = 0.9210340371976184f;  // ln(10000)/10
  union V16 { uint4 u[2]; unsigned short s[16]; };
  V16 qin, kin, qout, kout;
  qin.u[0] = *(const uint4*)(qkvb + srow);
  qin.u[1] = *(const uint4*)(qkvb + srow + 8);
  kin.u[0] = *(const uint4*)(qkvb + srow + 1024);
  kin.u[1] = *(const uint4*)(qkvb + srow + 1024 + 8);
#pragma unroll
  for (int p = 0; p < 8; ++p) {
    int d0 = dc * 16 + 2 * p;
    float qx0 = b2f(qin.s[2 * p]), qx1 = b2f(qin.s[2 * p + 1]);
    float kx0 = b2f(kin.s[2 * p]), kx1 = b2f(kin.s[2 * p + 1]);
    float qo0, qo1, ko0, ko1;
    if (d0 >= 60) { qo0 = qx0; qo1 = qx1; ko0 = kx0; ko1 = kx1; }
    else {
      int region = d0 / 20;
      int j0 = d0 - region * 20;
      int pos = region == 0 ? dpos : (region == 1 ? hpos : wpos);
      float fp = (float)pos;
      int i0 = j0 % 10, i1 = (j0 + 1) % 10;
      float f0 = expf(-LG * (float)i0) * fp;
      float f1 = expf(-LG * (float)i1) * fp;
      float c0 = cosf(f0), s0 = sinf(f0), c1 = cosf(f1), s1 = sinf(f1);
      qo0 = qx0 * c0 - qx1 * s0; qo1 = qx1 * c1 + qx0 * s1;
      ko0 = kx0 * c0 - kx1 * s0; ko1 = kx1 * c1 + kx0 * s1;
    }
    // fold attention scale (1/8) AND log2(e) into Q: scores in log2-space
    const float QS = 0.18033688011112042f;   // 0.125 * log2(e)
    qout.s[2 * p]     = f2b(qo0 * QS);
    qout.s[2 * p + 1] = f2b(qo1 * QS);
    kout.s[2 * p]     = f2b(ko0);
    kout.s[2 * p + 1] = f2b(ko1);
  }
  if (valid) {
    size_t drow = ((size_t)bh * NTOK + tg) * 64 + dc * 16;
    *(uint4*)(Qh + drow)     = qout.u[0];
    *(uint4*)(Qh + drow + 8) = qout.u[1];
    *(uint4*)(Kh + drow)     = kout.u[0];
    *(uint4*)(Kh + drow + 8) = kout.u[1];
  }
  __syncthreads();
  // V transpose out: thread = (dim, token-chunk)
  {
    int d = tid >> 2, tc = tid & 3;
    if (tile * 64 + tc * 16 < NTOK) {
      V16 o;
#pragma unroll
      for (int jj = 0; jj < 16; ++jj) o.s[jj] = Vs[(tc * 16 + jj) * 72 + d];
      unsigned short* dst = VT + ((size_t)bh * 64 + d) * NTOK + tile * 64 + tc * 16;
      *(uint4*)dst = o.u[0];
      *(uint4*)(dst + 8) = o.u[1];
    }
  }
}

// softmax block for one q-group: row-max -> defer-max rescale -> exp2 -> row-sum ->
// pack to bf16 + shfl-redistribute into the two PV B-fragments.
#define SM_BLOCK(S, MREG, LREG, OACC, PF)                                        \
  {                                                                              \
    float rmax = S[0][0];                                                        \
    _Pragma("unroll") for (int nt = 0; nt < 4; ++nt)                             \
      _Pragma("unroll") for (int rr = 0; rr < 4; ++rr)                           \
        rmax = fmaxf(rmax, S[nt][rr]);                                           \
    rmax = fmaxf(rmax, __shfl_xor(rmax, 16));                                    \
    rmax = fmaxf(rmax, __shfl_xor(rmax, 32));                                    \
    if (!__all(rmax - MREG <= 11.5f)) {                                          \
      float mn = fmaxf(MREG, rmax);                                              \
      float alpha = e2(MREG - mn);                                               \
      MREG = mn;                                                                 \
      LREG *= alpha;                                                             \
      _Pragma("unroll") for (int dt = 0; dt < 4; ++dt)                           \
        _Pragma("unroll") for (int rr = 0; rr < 4; ++rr) OACC[dt][rr] *= alpha;  \
    }                                                                            \
    float rsum = 0.0f;                                                           \
    _Pragma("unroll") for (int nt = 0; nt < 4; ++nt)                             \
      _Pragma("unroll") for (int rr = 0; rr < 4; ++rr) {                         \
        float pv = e2(S[nt][rr] - MREG);                                         \
        S[nt][rr] = pv;                                                          \
        rsum += pv;                                                              \
      }                                                                          \
    rsum += __shfl_xor(rsum, 16);                                                \
    rsum += __shfl_xor(rsum, 32);                                                \
    LREG += rsum;                                                                \
    unsigned pk01[4], pk23[4];                                                   \
    _Pragma("unroll") for (int nt = 0; nt < 4; ++nt) {                           \
      pk01[nt] = cvt2(S[nt][0], S[nt][1]);                                       \
      pk23[nt] = cvt2(S[nt][2], S[nt][3]);                                       \
    }                                                                            \
    _Pragma("unroll") for (int kc = 0; kc < 2; ++kc) {                           \
      unsigned t0, t1;                                                           \
      t0 = __shfl(pk01[2 * kc], srcA); t1 = __shfl(pk01[2 * kc + 1], srcA);      \
      PF[kc].u[0] = hi ? t1 : t0;                                                \
      t0 = __shfl(pk23[2 * kc], srcA); t1 = __shfl(pk23[2 * kc + 1], srcA);      \
      PF[kc].u[1] = hi ? t1 : t0;                                                \
      t0 = __shfl(pk01[2 * kc], srcB); t1 = __shfl(pk01[2 * kc + 1], srcB);      \
      PF[kc].u[2] = hi ? t1 : t0;                                                \
      t0 = __shfl(pk23[2 * kc], srcB); t1 = __shfl(pk23[2 * kc + 1], srcB);      \
      PF[kc].u[3] = hi ? t1 : t0;                                                \
    }                                                                            \
  }

// ---------------- flash attention v8: QBLK=128 + counted-vmcnt tri-buffer ------------
// grid (32 bh, 13 q-tiles, 2 kv). Tri-buffered K/V LDS (48 KB), stage-ahead-2,
// vmcnt(4) counted gate (never drains mid-loop).
__global__ __launch_bounds__(256, 3) void flash6_k(const unsigned short* __restrict__ Qh,
                                                   const unsigned short* __restrict__ Kh,
                                                   const unsigned short* __restrict__ VT,
                                                   unsigned short* __restrict__ Opart,
                                                   float2* __restrict__ ml) {
  __shared__ unsigned short Ks[3][64 * 64];
  __shared__ unsigned short Vs[3][64 * 64];
  const int bh = blockIdx.x, qt = blockIdx.y, kv = blockIdx.z;
  const int kt0 = kv ? 13 : 0, kt1 = kv ? 25 : 13;
  const int tid = threadIdx.x, lane = tid & 63, w = tid >> 6;
  const int l15 = lane & 15, l4 = lane >> 4;
  const size_t hb = (size_t)bh * NTOK * 64;
  const unsigned short* kgp = Kh + hb;
  const unsigned short* vbp = VT + (size_t)bh * 64 * NTOK;

  const int srow0 = w * 8 + (lane >> 3);          // it=0 row
  const int scg0  = (lane & 7) ^ (srow0 & 7);
  const int srow1 = srow0 + 32;                   // it=1 row
  const int scg1  = (lane & 7) ^ (srow1 & 7);

  auto stage = [&](int buf, int kc) {
    async16(kgp + (size_t)(kc + srow0) * 64 + scg0 * 8, &Ks[buf][(size_t)w * 512]);
    async16(kgp + (size_t)(kc + srow1) * 64 + scg1 * 8, &Ks[buf][(size_t)(w + 4) * 512]);
    async16(vbp + (size_t)srow0 * NTOK + kc + scg0 * 8, &Vs[buf][(size_t)w * 512]);
    async16(vbp + (size_t)srow1 * NTOK + kc + scg1 * 8, &Vs[buf][(size_t)(w + 4) * 512]);
  };

  // two q-groups of 16 rows each per wave
  const int qrow0 = qt * 128 + w * 32 + l15;
  const int qrow1 = qrow0 + 16;
  const int qrc0 = qrow0 < NTOK ? qrow0 : NTOK - 1;
  const int qrc1 = qrow1 < NTOK ? qrow1 : NTOK - 1;
  bf16x8 qa0 = *(const bf16x8*)(Qh + hb + (size_t)qrc0 * 64 + l4 * 8);
  bf16x8 qa1 = *(const bf16x8*)(Qh + hb + (size_t)qrc0 * 64 + 32 + l4 * 8);
  bf16x8 qb0 = *(const bf16x8*)(Qh + hb + (size_t)qrc1 * 64 + l4 * 8);
  bf16x8 qb1 = *(const bf16x8*)(Qh + hb + (size_t)qrc1 * 64 + 32 + l4 * 8);

  f32x4 oaccA[4] = {}, oaccB[4] = {};
  float mA = -1e30f, lA = 0.0f, mB = -1e30f, lB = 0.0f;

  // prologue: stage tiles kt0, kt0+1
  stage(0, kt0 * 64);
  stage(1, (kt0 + 1) * 64);

  const int h7 = l15 & 7;
  const int p1 = (l4 ^ h7) * 8;          // phys offset of logical chunk l4
  const int p2 = ((l4 + 4) ^ h7) * 8;    // phys offset of logical chunk l4+4
  const int srcA = ((l4 & 1) << 5) | l15;
  const int srcB = srcA + 16;
  const bool hi = (l4 >> 1) != 0;

  int cur = 0;
  for (int kt = kt0; kt < kt1; ++kt) {
    const int kb = kt * 64;
    // counted gate: retire tile kt (tile kt+1 stays in flight)
    if (kt + 1 < kt1) {
      asm volatile("s_waitcnt vmcnt(4)" ::: "memory");
    } else {
      asm volatile("s_waitcnt vmcnt(0)" ::: "memory");
    }
    __builtin_amdgcn_s_barrier();
    __builtin_amdgcn_sched_barrier(0);   // ds_reads must not hoist above barrier
    if (kt + 2 < kt1) {
      int nxt2 = cur + 2; if (nxt2 >= 3) nxt2 -= 3;
      stage(nxt2, (kt + 2) * 64);
    }

    bf16x8 kc0[4], kc1[4];
#pragma unroll
    for (int nt = 0; nt < 4; ++nt) {
      const unsigned short* kr = &Ks[cur][(nt * 16 + l15) * 64];
      kc0[nt] = *(const bf16x8*)(kr + p1);
      kc1[nt] = *(const bf16x8*)(kr + p2);
    }
    f32x4 sA[4] = {}, sB[4] = {};
    __builtin_amdgcn_s_setprio(1);
#pragma unroll
    for (int nt = 0; nt < 4; ++nt) {
      sA[nt] = __builtin_amdgcn_mfma_f32_16x16x32_bf16(kc0[nt], qa0, sA[nt], 0, 0, 0);
      sA[nt] = __builtin_amdgcn_mfma_f32_16x16x32_bf16(kc1[nt], qa1, sA[nt], 0, 0, 0);
      sB[nt] = __builtin_amdgcn_mfma_f32_16x16x32_bf16(kc0[nt], qb0, sB[nt], 0, 0, 0);
      sB[nt] = __builtin_amdgcn_mfma_f32_16x16x32_bf16(kc1[nt], qb1, sB[nt], 0, 0, 0);
    }
    __builtin_amdgcn_s_setprio(0);
    bf16x8 vf0[4], vf1[4];
#pragma unroll
    for (int dt = 0; dt < 4; ++dt) {
      const unsigned short* vr = &Vs[cur][(dt * 16 + l15) * 64];
      vf0[dt] = *(const bf16x8*)(vr + p1);
      vf1[dt] = *(const bf16x8*)(vr + p2);
    }

    if (kb + 64 > NTOK) {
#pragma unroll
      for (int nt = 0; nt < 4; ++nt)
#pragma unroll
        for (int rr = 0; rr < 4; ++rr)
          if (kb + nt * 16 + l4 * 4 + rr >= NTOK) { sA[nt][rr] = -1e30f; sB[nt][rr] = -1e30f; }
    }

    union PB { unsigned u[4]; bf16x8 v; } pfA[2], pfB[2];
    SM_BLOCK(sA, mA, lA, oaccA, pfA)
    __builtin_amdgcn_s_setprio(1);
#pragma unroll
    for (int dt = 0; dt < 4; ++dt) {
      oaccA[dt] = __builtin_amdgcn_mfma_f32_16x16x32_bf16(vf0[dt], pfA[0].v, oaccA[dt], 0, 0, 0);
      oaccA[dt] = __builtin_amdgcn_mfma_f32_16x16x32_bf16(vf1[dt], pfA[1].v, oaccA[dt], 0, 0, 0);
    }
    __builtin_amdgcn_s_setprio(0);
    SM_BLOCK(sB, mB, lB, oaccB, pfB)
    __builtin_amdgcn_s_setprio(1);
#pragma unroll
    for (int dt = 0; dt < 4; ++dt) {
      oaccB[dt] = __builtin_amdgcn_mfma_f32_16x16x32_bf16(vf0[dt], pfB[0].v, oaccB[dt], 0, 0, 0);
      oaccB[dt] = __builtin_amdgcn_mfma_f32_16x16x32_bf16(vf1[dt], pfB[1].v, oaccB[dt], 0, 0, 0);
    }
    __builtin_amdgcn_s_setprio(0);
    cur = cur + 1 == 3 ? 0 : cur + 1;
  }

  // epilogue: per q-group O~^T -> LDS transpose (per-wave private region, aliased
  // into Ks after barrier) -> bf16 partial. Same-wave ds write->read, in-order.
  __syncthreads();                          // full drain: all waves done with Ks/Vs
  unsigned short* Os = &Ks[0][0];           // 4 waves * 1152 ushorts < 12288
#pragma unroll
  for (int dt = 0; dt < 4; ++dt)
#pragma unroll
    for (int rr = 0; rr < 4; ++rr)
      Os[w * 1152 + l15 * 72 + dt * 16 + l4 * 4 + rr] = f2b(oaccA[dt][rr]);
  if (qrow0 < NTOK) {
    uint4 a  = *(const uint4*)&Os[w * 1152 + l15 * 72 + l4 * 16];
    uint4 bq = *(const uint4*)&Os[w * 1152 + l15 * 72 + l4 * 16 + 8];
    unsigned short* op = Opart + ((size_t)(kv * 32 + bh) * NTOK + qrow0) * 64;
    *(uint4*)(op + l4 * 16) = a;
    *(uint4*)(op + l4 * 16 + 8) = bq;
    if (l4 == 0) ml[(size_t)(kv * 32 + bh) * NTOK + qrow0] = make_float2(mA, lA);
  }
  __builtin_amdgcn_sched_barrier(0);        // keep qg=0 reads before qg=1 writes
#pragma unroll
  for (int dt = 0; dt < 4; ++dt)
#pragma unroll
    for (int rr = 0; rr < 4; ++rr)
      Os[w * 1152 + l15 * 72 + dt * 16 + l4 * 4 + rr] = f2b(oaccB[dt][rr]);
  if (qrow1 < NTOK) {
    uint4 a  = *(const uint4*)&Os[w * 1152 + l15 * 72 + l4 * 16];
    uint4 bq = *(const uint4*)&Os[w * 1152 + l15 * 72 + l4 * 16 + 8];
    unsigned short* op = Opart + ((size_t)(kv * 32 + bh) * NTOK + qrow1) * 64;
    *(uint4*)(op + l4 * 16) = a;
    *(uint4*)(op + l4 * 16 + 8) = bq;
    if (l4 == 0) ml[(size_t)(kv * 32 + bh) * NTOK + qrow1] = make_float2(mB, lB);
  }
}

// ---------------- combine the two KV-split partials -> ob ----------------------------
__global__ __launch_bounds__(256) void fcomb_k(const unsigned short* __restrict__ Op,
                                               const float2* __restrict__ ml,
                                               unsigned short* __restrict__ O) {
  const int bh = blockIdx.x, qt = blockIdx.y;
  const int tid = threadIdx.x;
  const int qr = qt * 64 + (tid >> 2);
  const int dc = (tid & 3) * 16;
  if (qr >= NTOK) return;
  const int b = bh >> 4, head = bh & 15;
  float2 a0 = ml[(size_t)bh * NTOK + qr];          // kv=0: (m, l)
  float2 a1 = ml[(size_t)(32 + bh) * NTOK + qr];   // kv=1
  float M = fmaxf(a0.x, a1.x);
  float w0 = e2(a0.x - M), w1 = e2(a1.x - M);
  float inv = 1.0f / (a0.y * w0 + a1.y * w1);
  w0 *= inv; w1 *= inv;
  union V16 { uint4 u[2]; unsigned short s[16]; } p0, p1, o;
  const unsigned short* q0 = Op + ((size_t)bh * NTOK + qr) * 64 + dc;
  const unsigned short* q1 = Op + ((size_t)(32 + bh) * NTOK + qr) * 64 + dc;
  p0.u[0] = *(const uint4*)q0;       p0.u[1] = *(const uint4*)(q0 + 8);
  p1.u[0] = *(const uint4*)q1;       p1.u[1] = *(const uint4*)(q1 + 8);
#pragma unroll
  for (int j = 0; j < 16; ++j) o.s[j] = f2b(b2f(p0.s[j]) * w0 + b2f(p1.s[j]) * w1);
  unsigned short* dst = O + ((size_t)(b * NTOK + qr)) * HID + head * 64 + dc;
  *(uint4*)dst = o.u[0];
  *(uint4*)(dst + 8) = o.u[1];
}

// ---------------- host launch ----------------
extern "C" void kernel_launch(void* const* d_in, const int* in_sizes, int n_in,
                              void* d_out, int out_size, void* d_ws, size_t ws_size,
                              hipStream_t stream) {
  (void)in_sizes; (void)n_in; (void)out_size; (void)ws_size;
  const float* pv      = (const float*)d_in[0];
  const float* patch_w = (const float*)d_in[1];
  const float* patch_b = (const float*)d_in[2];
  const float* ln1_g   = (const float*)d_in[3];
  const float* ln1_b   = (const float*)d_in[4];
  const float* qw = (const float*)d_in[5];
  const float* qb = (const float*)d_in[6];
  const float* kw = (const float*)d_in[7];
  const float* kb = (const float*)d_in[8];
  const float* vw = (const float*)d_in[9];
  const float* vb = (const float*)d_in[10];
  const float* pw = (const float*)d_in[11];
  const float* pb = (const float*)d_in[12];
  const float* ln2_g = (const float*)d_in[13];
  const float* ln2_b = (const float*)d_in[14];
  const float* fc1w = (const float*)d_in[15];
  const float* fc1b = (const float*)d_in[16];
  const float* fc2w = (const float*)d_in[17];
  const float* fc2b = (const float*)d_in[18];
  const float* lnf_g = (const float*)d_in[19];
  const float* lnf_b = (const float*)d_in[20];

  char* wsp = (char*)d_ws;
  auto alloc = [&](size_t bytes) {
    char* p = wsp;
    wsp += (bytes + 255) & ~(size_t)255;
    return p;
  };
  unsigned short* wPatch = (unsigned short*)alloc((size_t)1024 * 1536 * 2);
  unsigned short* wQKV   = (unsigned short*)alloc((size_t)NLAYER * 3072 * 1024 * 2);
  unsigned short* wP     = (unsigned short*)alloc((size_t)NLAYER * HID * HID * 2);
  unsigned short* wF1    = (unsigned short*)alloc((size_t)NLAYER * MLPD * HID * 2);
  unsigned short* wF2    = (unsigned short*)alloc((size_t)NLAYER * HID * MLPD * 2);
  float*          qkvbias = (float*)alloc((size_t)NLAYER * 3072 * 4);
  unsigned short* Aim  = (unsigned short*)alloc((size_t)ROWS * CONVK * 2);
  float*          h    = (float*)alloc((size_t)ROWS * HID * 4);
  unsigned short* xnb  = (unsigned short*)alloc((size_t)ROWS * HID * 2);
  unsigned short* qkvo = (unsigned short*)alloc((size_t)ROWS * 3072 * 2);
  unsigned short* Qh   = (unsigned short*)alloc((size_t)ROWS * HID * 2 + 8192);
  unsigned short* Kh   = (unsigned short*)alloc((size_t)ROWS * HID * 2 + 8192);
  unsigned short* VT   = (unsigned short*)alloc((size_t)ROWS * HID * 2 + 8192);
  unsigned short* ob   = (unsigned short*)alloc((size_t)ROWS * HID * 2);
  unsigned short* mb   = (unsigned short*)alloc((size_t)ROWS * MLPD * 2);

  // Aliasing plan (all stream-ordered):
  //  part  (=Qh): conv z0..3 (25.7MB spans Qh..ob, consumed by redln before qkvprep),
  //               fc2 z0..3 (same span; consumed before next-layer writes).
  //  partM (=mb): proj z0..3 (ob is proj's A, partials must NOT hit ob).
  //  Opart/ml (=mb): flash partials, consumed by fcomb before proj overwrites mb.
  //  qkv + fc1 are single-z with fused bias(+gelu) epilogues: write final outputs
  //  (qkvo / mb) directly -- no partial buffers, no reduce pass.
  unsigned short* part  = Qh;
  unsigned short* partM = mb;
  unsigned short* Opart = mb;
  float2*         mlbuf = (float2*)(mb + (size_t)2 * 32 * NTOK * 64);
  const size_t MNs = (size_t)ROWS * HID;

  auto cast = [&](const float* s, unsigned short* d, long long n) {
    long long n4 = n / 4;
    int grid = (int)((n4 + 255) / 256);
    if (grid > 16384) grid = 16384;
    cast4_k<<<grid, 256, 0, stream>>>(s, d, n4);
  };
  cast(patch_w, wPatch, (long long)1024 * 1536);
  castqkv_k<<<dim3(4096, 3), 256, 0, stream>>>(qw, kw, vw, wQKV);
  cast(pw, wP, (long long)NLAYER * HID * HID);
  cast(fc1w, wF1, (long long)NLAYER * MLPD * HID);
  cast(fc2w, wF2, (long long)NLAYER * HID * MLPD);
  biascat_k<<<48, 256, 0, stream>>>(qb, kb, vb, qkvbias);

  im2col_k<<<(ROWS * CONVK) / 256, 256, 0, stream>>>(pv, Aim);
  // conv GEMM split-K x4 (kChunk 384 = 6 K-tiles) -> h = sum+bias, xnb = LN1_0(h)
  gemm256<0><<<dim3(4, 13, 4), 512, 0, stream>>>(
      Aim, wPatch, part, ROWS, HID, CONVK, 384, MNs, nullptr);
  redln_k<4, 0, 0><<<ROWS, 256, 0, stream>>>(
      part, patch_b, nullptr, ln1_g, ln1_b, h, xnb, nullptr, MNs);

  for (int i = 0; i < NLAYER; ++i) {
    // qkv: single-K GEMM with fused bias -> qkvo directly
    gemm256<1><<<dim3(12, 13, 1), 512, 0, stream>>>(
        xnb, wQKV + (size_t)i * 3072 * 1024, qkvo, ROWS, 3072, HID, 1024,
        0, qkvbias + i * 3072);
    qkvprep_k<<<dim3(25, 32), 256, 0, stream>>>(qkvo, Qh, Kh, VT);
    flash6_k<<<dim3(32, 13, 2), 256, 0, stream>>>(Qh, Kh, VT, Opart, mlbuf);
    fcomb_k<<<dim3(32, 25), 256, 0, stream>>>(Opart, mlbuf, ob);
    // proj split-K x4 (kChunk 256; partials in mb, NOT ob) -> h += proj+pb, xnb = LN2(h)
    gemm256<0><<<dim3(4, 13, 4), 512, 0, stream>>>(
        ob, wP + (size_t)i * HID * HID, partM, ROWS, HID, HID, 256, MNs, nullptr);
    redln_k<4, 1, 0><<<ROWS, 256, 0, stream>>>(
        partM, pb + i * HID, h, ln2_g + i * HID, ln2_b + i * HID, h, xnb, nullptr, MNs);
    // fc1: single-K GEMM with fused bias+gelu -> mb directly
    gemm256<2><<<dim3(16, 13, 1), 512, 0, stream>>>(
        xnb, wF1 + (size_t)i * MLPD * HID, mb, ROWS, MLPD, HID, 1024,
        0, fc1b + i * MLPD);
    // fc2 split-K x4 (kChunk 1024) -> h += fc2+bias, then LN1(next) or LNf->out
    gemm256<0><<<dim3(4, 13, 4), 512, 0, stream>>>(
        mb, wF2 + (size_t)i * HID * MLPD, part, ROWS, HID, MLPD, 1024, MNs, nullptr);
    if (i < NLAYER - 1) {
      redln_k<4, 1, 0><<<ROWS, 256, 0, stream>>>(
          part, fc2b + i * HID, h, ln1_g + (i + 1) * HID, ln1_b + (i + 1) * HID,
          h, xnb, nullptr, MNs);
    } else {
      redln_k<4, 1, 1><<<ROWS, 256, 0, stream>>>(
          part, fc2b + i * HID, h, lnf_g, lnf_b, nullptr, nullptr, (float*)d_out, MNs);
    }
  }
}